// Round 3
// baseline (5871.419 us; speedup 1.0000x reference)
//
#include <hip/hip_runtime.h>
#include <math.h>

#define HW 65536
#define Wd 256
#define Hd 256
#define Bn 4

// stats layout per channel: [4 slots of sum][4 slots of sum2]  (float)
__device__ __forceinline__ void atomAddF(float* p, float v){
    __hip_atomic_fetch_add(p, v, __ATOMIC_RELAXED, __HIP_MEMORY_SCOPE_AGENT);
}

__global__ void zero_k(float* __restrict__ p, int n){
    for(int i = blockIdx.x*256 + threadIdx.x; i < n; i += gridDim.x*256) p[i] = 0.f;
}

// ================= vectorized direct 3x3 conv =================
// Each thread computes PX horizontally-consecutive pixels for COB output chans.
// Weights staged in LDS (broadcast ds_read). Channel loop software-pipelined 2x
// with double-buffered row registers so next-channel global loads hide under FMAs.
template<int CIN1,int CIN2,int COUT,int COB,int DIL,int PX>
__global__ __launch_bounds__(256) void conv3_k(
    const float* __restrict__ inA, long long a_bs,
    const float* __restrict__ inB,
    const float* __restrict__ add_in,
    const float* __restrict__ w, const float* __restrict__ bias,
    const float* __restrict__ scale_c, const float* __restrict__ scale_p,
    float* __restrict__ out, float* __restrict__ stats)
{
    constexpr int CIN = CIN1 + CIN2;
    constexpr int SP = 2*DIL + PX;
    constexpr int TPR = 64/PX;        // threads per 64-wide row
    constexpr int ROWS = 256/TPR;     // rows per block
    constexpr int IYB = Hd/ROWS;      // row-blocks
    int tx = threadIdx.x % TPR, ty = threadIdx.x / TPR;
    int j0 = blockIdx.x*64 + tx*PX;
    int iy = blockIdx.y % IYB;
    int chunk = blockIdx.y / IYB;
    int i = iy*ROWS + ty;
    int b = blockIdx.z;
    int o0 = chunk*COB;

    // stage this chunk's weights into LDS (contiguous block of COB*CIN*9)
    __shared__ float wl[COB*CIN*9];
    for(int t=threadIdx.x; t<COB*CIN*9; t+=256)
        wl[t] = w[(size_t)o0*CIN*9 + t];
    __syncthreads();

    float acc[COB][PX];
#pragma unroll
    for(int o=0;o<COB;o++){
        float bv = bias ? bias[o0+o] : 0.f;
#pragma unroll
        for(int q=0;q<PX;q++) acc[o][q] = bv;
    }

    const float* spb = scale_p ? scale_p + (size_t)b*HW : nullptr;

    auto load_rows = [&](float (&r)[3][SP], int c){
        const float* cb;
        if (CIN2 == 0 || c < CIN1) cb = inA + (size_t)b*a_bs + (size_t)c*HW;
        else                       cb = inB + ((size_t)b*CIN2 + (c-CIN1))*HW;
        const float* ab = add_in ? add_in + (size_t)b*a_bs + (size_t)c*HW : nullptr;
        float sc = scale_c ? scale_c[b*CIN + c] : 1.f;
#pragma unroll
        for(int kh=0;kh<3;kh++){
#pragma unroll
            for(int t=0;t<SP;t++) r[kh][t] = 0.f;
            int ii = i + (kh-1)*DIL;
            if (ii < 0 || ii >= Hd) continue;
            const float* row = cb + ii*Wd;
#pragma unroll
            for(int q4=0;q4<PX/4;q4++){
                float4 c4 = *(const float4*)(row + j0 + q4*4);
                r[kh][DIL+q4*4+0]=c4.x; r[kh][DIL+q4*4+1]=c4.y;
                r[kh][DIL+q4*4+2]=c4.z; r[kh][DIL+q4*4+3]=c4.w;
            }
#pragma unroll
            for(int t=0;t<DIL;t++){
                int jl = j0 - DIL + t;
                if (jl >= 0) r[kh][t] = row[jl];
                int jr = j0 + PX + t;
                if (jr < Wd) r[kh][DIL+PX+t] = row[jr];
            }
            if (ab){
                const float* arow = ab + ii*Wd;
#pragma unroll
                for(int q4=0;q4<PX/4;q4++){
                    float4 a4 = *(const float4*)(arow + j0 + q4*4);
                    r[kh][DIL+q4*4+0]+=a4.x; r[kh][DIL+q4*4+1]+=a4.y;
                    r[kh][DIL+q4*4+2]+=a4.z; r[kh][DIL+q4*4+3]+=a4.w;
                }
#pragma unroll
                for(int t=0;t<DIL;t++){
                    int jl = j0 - DIL + t;
                    if (jl >= 0) r[kh][t] += arow[jl];
                    int jr = j0 + PX + t;
                    if (jr < Wd) r[kh][DIL+PX+t] += arow[jr];
                }
            }
            if (spb){
                const float* srow = spb + ii*Wd;
#pragma unroll
                for(int q4=0;q4<PX/4;q4++){
                    float4 s4 = *(const float4*)(srow + j0 + q4*4);
                    r[kh][DIL+q4*4+0]*=s4.x; r[kh][DIL+q4*4+1]*=s4.y;
                    r[kh][DIL+q4*4+2]*=s4.z; r[kh][DIL+q4*4+3]*=s4.w;
                }
#pragma unroll
                for(int t=0;t<DIL;t++){
                    int jl = j0 - DIL + t;
                    if (jl >= 0) r[kh][t] *= srow[jl];
                    int jr = j0 + PX + t;
                    if (jr < Wd) r[kh][DIL+PX+t] *= srow[jr];
                }
            }
            if (scale_c){
#pragma unroll
                for(int t=0;t<SP;t++) r[kh][t] *= sc;
            }
        }
    };

    auto do_fma = [&](float (&r)[3][SP], int c){
#pragma unroll
        for(int o=0;o<COB;o++){
#pragma unroll
            for(int kh=0;kh<3;kh++){
#pragma unroll
                for(int kw=0;kw<3;kw++){
                    float ww = wl[(o*CIN + c)*9 + kh*3 + kw];
#pragma unroll
                    for(int q=0;q<PX;q++)
                        acc[o][q] = fmaf(ww, r[kh][kw*DIL + q], acc[o][q]);
                }
            }
        }
    };

    // software-pipelined channel loop (CIN is even for all instantiations)
    float rA[3][SP], rB[3][SP];
    load_rows(rA, 0);
    for(int c=0;c<CIN;c+=2){
        load_rows(rB, c+1);
        do_fma(rA, c);
        if (c+2 < CIN) load_rows(rA, c+2);
        do_fma(rB, c+1);
    }

    float* ob = out + ((size_t)b*COUT + o0)*HW + i*Wd + j0;
#pragma unroll
    for(int o=0;o<COB;o++){
#pragma unroll
        for(int q4=0;q4<PX/4;q4++){
            float4 v; v.x=acc[o][q4*4+0]; v.y=acc[o][q4*4+1];
            v.z=acc[o][q4*4+2]; v.w=acc[o][q4*4+3];
            *(float4*)(ob + (size_t)o*HW + q4*4) = v;
        }
    }

    if (stats){
#pragma unroll
        for(int o=0;o<COB;o++){
            float s = 0.f, s2 = 0.f;
#pragma unroll
            for(int q=0;q<PX;q++){ s += acc[o][q]; s2 += acc[o][q]*acc[o][q]; }
#pragma unroll
            for(int d=32;d>0;d>>=1){
                s  += __shfl_down(s,  d, 64);
                s2 += __shfl_down(s2, d, 64);
            }
            if ((threadIdx.x & 63) == 0){
                float* pc = stats + (size_t)(o0+o)*8 + ((threadIdx.x>>6)&3);
                atomAddF(pc,   s);
                atomAddF(pc+4, s2);
            }
        }
    }
}

// ================= conv 1x1 : PX=4 pixels/thread, COB-chunked channels =========
// SPLIT=1: input is the channel-concat of 4 buffers of 16 channels each.
template<int CIN,int COUT,int COB,int SPLIT>
__global__ __launch_bounds__(256) void conv1x1_k(
    const float* __restrict__ in0, const float* __restrict__ in1,
    const float* __restrict__ in2, const float* __restrict__ in3,
    const float* __restrict__ w, const float* __restrict__ bias,
    float* __restrict__ out, float* __restrict__ stats)
{
    int p = (blockIdx.x*256 + threadIdx.x)*4;
    int chunk = blockIdx.y;
    int b = blockIdx.z;
    int o0 = chunk*COB;

    float acc[COB][4];
#pragma unroll
    for(int o=0;o<COB;o++){
        float bv = bias ? bias[o0+o] : 0.f;
#pragma unroll
        for(int q=0;q<4;q++) acc[o][q] = bv;
    }

#pragma unroll 8
    for(int c=0;c<CIN;c++){
        const float* cb;
        if (SPLIT){
            const float* s = (c<16)?in0:(c<32)?in1:(c<48)?in2:in3;
            cb = s + ((size_t)b*16 + (c&15))*HW;
        } else {
            cb = in0 + ((size_t)b*CIN + c)*HW;
        }
        float4 v = *(const float4*)(cb + p);
#pragma unroll
        for(int o=0;o<COB;o++){
            float ww = w[(size_t)(o0+o)*CIN + c];
            acc[o][0] = fmaf(ww, v.x, acc[o][0]);
            acc[o][1] = fmaf(ww, v.y, acc[o][1]);
            acc[o][2] = fmaf(ww, v.z, acc[o][2]);
            acc[o][3] = fmaf(ww, v.w, acc[o][3]);
        }
    }

    float* ob = out + ((size_t)b*COUT + o0)*HW + p;
#pragma unroll
    for(int o=0;o<COB;o++){
        float4 v; v.x=acc[o][0]; v.y=acc[o][1]; v.z=acc[o][2]; v.w=acc[o][3];
        *(float4*)(ob + (size_t)o*HW) = v;
    }

    if (stats){
#pragma unroll
        for(int o=0;o<COB;o++){
            float s = 0.f, s2 = 0.f;
#pragma unroll
            for(int q=0;q<4;q++){ s += acc[o][q]; s2 += acc[o][q]*acc[o][q]; }
#pragma unroll
            for(int d=32;d>0;d>>=1){
                s  += __shfl_down(s,  d, 64);
                s2 += __shfl_down(s2, d, 64);
            }
            if ((threadIdx.x & 63) == 0){
                float* pc = stats + (size_t)(o0+o)*8 + ((threadIdx.x>>6)&3);
                atomAddF(pc,   s);
                atomAddF(pc+4, s2);
            }
        }
    }
}

// ===== BN apply, float4 (+extras with batch stride, +relu); m/r from fused stats =====
__global__ void bn_apply_k(const float* __restrict__ x, const float* __restrict__ stats, int C,
                           const float* __restrict__ e1, long long e1_bs,
                           const float* __restrict__ e2, long long e2_bs,
                           float* __restrict__ out, int relu)
{
    int p = (blockIdx.x*256 + threadIdx.x)*4;
    int c = blockIdx.y, b = blockIdx.z;
    const float* pc = stats + (size_t)c*8;
    float s  = pc[0]+pc[1]+pc[2]+pc[3];
    float s2 = pc[4]+pc[5]+pc[6]+pc[7];
    const float inv_n = 1.f / (float)((long long)Bn*HW);
    float m = s*inv_n;
    float r = rsqrtf(fmaxf(s2*inv_n - m*m, 0.f) + 1e-5f);
    size_t idx = ((size_t)b*C + c)*HW + p;
    float4 v = *(const float4*)(x + idx);
    v.x = (v.x-m)*r; v.y = (v.y-m)*r; v.z = (v.z-m)*r; v.w = (v.w-m)*r;
    if (e1){
        float4 a = *(const float4*)(e1 + (size_t)b*e1_bs + (size_t)c*HW + p);
        v.x+=a.x; v.y+=a.y; v.z+=a.z; v.w+=a.w;
    }
    if (e2){
        float4 a = *(const float4*)(e2 + (size_t)b*e2_bs + (size_t)c*HW + p);
        v.x+=a.x; v.y+=a.y; v.z+=a.z; v.w+=a.w;
    }
    if (relu){
        v.x=fmaxf(v.x,0.f); v.y=fmaxf(v.y,0.f); v.z=fmaxf(v.z,0.f); v.w=fmaxf(v.w,0.f);
    }
    *(float4*)(out + idx) = v;
}

// ================= deformable conv (exact reference boundary semantics) ============
__global__ void deform_k(const float* __restrict__ t, const float* __restrict__ off,
                         const float* __restrict__ w, float* __restrict__ out)
{
    int tx = threadIdx.x & 15, ty = threadIdx.x >> 4;
    int j = blockIdx.x*16 + tx;
    int i = blockIdx.y*16 + ty;
    int b = blockIdx.z;
    const float* tb = t + (size_t)b*16*HW;
    const float* ob = off + (size_t)b*18*HW + i*Wd + j;
    float acc[16];
#pragma unroll
    for(int o=0;o<16;o++) acc[o] = 0.f;

    for(int n=0;n<9;n++){
        float offx = ob[(size_t)(2*n)*HW];
        float offy = ob[(size_t)(2*n+1)*HW];
        float px = (float)(i + n/3) + offx;
        float py = (float)(j + n%3) + offy;
        float flx = floorf(px), fly = floorf(py);
        float qltx = fminf(fmaxf(flx,       0.f), 257.f);
        float qlty = fminf(fmaxf(fly,       0.f), 257.f);
        float qrbx = fminf(fmaxf(flx + 1.f, 0.f), 257.f);
        float qrby = fminf(fmaxf(fly + 1.f, 0.f), 257.f);
        if (px < 1.f || px > 256.f) px = flx;
        if (py < 1.f || py > 256.f) py = fly;
        px = fminf(fmaxf(px, 0.f), 257.f);
        py = fminf(fmaxf(py, 0.f), 257.f);
        float wx_lt = 1.f + (qltx - px);
        float wx_rb = 1.f - (qrbx - px);
        float wy_lt = 1.f + (qlty - py);
        float wy_rb = 1.f - (qrby - py);
        float glt = wx_lt*wy_lt, grb = wx_rb*wy_rb, glb = wx_lt*wy_rb, grt = wx_rb*wy_lt;
        int ix0 = (int)qltx - 1, iy0 = (int)qlty - 1;
        int ix1 = (int)qrbx - 1, iy1 = (int)qrby - 1;
        bool vx0 = (ix0>=0 && ix0<Hd), vx1 = (ix1>=0 && ix1<Hd);
        bool vy0 = (iy0>=0 && iy0<Wd), vy1 = (iy1>=0 && iy1<Wd);
        int i00 = ix0*Wd+iy0, i01 = ix0*Wd+iy1, i10 = ix1*Wd+iy0, i11 = ix1*Wd+iy1;
        float vals[16];
#pragma unroll
        for(int c=0;c<16;c++){
            const float* tc = tb + (size_t)c*HW;
            float v00 = (vx0&&vy0) ? tc[i00] : 0.f;
            float v11 = (vx1&&vy1) ? tc[i11] : 0.f;
            float v01 = (vx0&&vy1) ? tc[i01] : 0.f;
            float v10 = (vx1&&vy0) ? tc[i10] : 0.f;
            vals[c] = glt*v00 + grb*v11 + glb*v01 + grt*v10;
        }
#pragma unroll
        for(int o=0;o<16;o++){
            float a = acc[o];
#pragma unroll
            for(int c=0;c<16;c++) a += w[(o*16+c)*9 + n] * vals[c];
            acc[o] = a;
        }
    }
    float* outb = out + (size_t)b*16*HW + i*Wd + j;
#pragma unroll
    for(int o=0;o<16;o++) outb[(size_t)o*HW] = acc[o];
}

// ================= CBAM pieces =================
__global__ void pool_k(const float* __restrict__ x, float* __restrict__ pavg, float* __restrict__ pmax)
{
    int bc = blockIdx.x;
    int tid = threadIdx.x;
    const float* p = x + (size_t)bc*HW;
    float s = 0.f, mx = -1e30f;
    for(int i=tid;i<HW;i+=256){ float v = p[i]; s += v; mx = fmaxf(mx, v); }
    __shared__ float sh[512];
    sh[tid] = s; sh[256+tid] = mx;
    __syncthreads();
    for(int o=128;o>0;o>>=1){
        if (tid < o){ sh[tid] += sh[tid+o]; sh[256+tid] = fmaxf(sh[256+tid], sh[256+tid+o]); }
        __syncthreads();
    }
    if (tid==0){ pavg[bc] = sh[0] / (float)HW; pmax[bc] = sh[256]; }
}

__global__ void ca_k(const float* __restrict__ pavg, const float* __restrict__ pmax,
                     const float* __restrict__ w1, const float* __restrict__ w2,
                     float* __restrict__ ca)
{
    int b = blockIdx.x;
    int tid = threadIdx.x;   // 64 threads
    __shared__ float ha[4], hm[4];
    if (tid < 4){
        float sa = 0.f, sm = 0.f;
        for(int c=0;c<64;c++){
            sa += w1[tid*64+c] * pavg[b*64+c];
            sm += w1[tid*64+c] * pmax[b*64+c];
        }
        ha[tid] = fmaxf(sa, 0.f);
        hm[tid] = fmaxf(sm, 0.f);
    }
    __syncthreads();
    float s = 0.f;
    for(int h=0;h<4;h++) s += w2[tid*4+h] * (ha[h] + hm[h]);
    ca[b*64+tid] = 1.f / (1.f + expf(-s));
}

__global__ void spstats_k(const float* __restrict__ x, const float* __restrict__ ca,
                          float* __restrict__ spm, float* __restrict__ spx)
{
    int p = blockIdx.x*256 + threadIdx.x;
    int b = blockIdx.y;
    const float* xb = x + (size_t)b*64*HW + p;
    const float* cb = ca + b*64;
    float s = 0.f, mx = -1e30f;
    for(int c=0;c<64;c++){
        float v = xb[(size_t)c*HW] * cb[c];
        s += v; mx = fmaxf(mx, v);
    }
    spm[(size_t)b*HW+p] = s * (1.f/64.f);
    spx[(size_t)b*HW+p] = mx;
}

__global__ void spconv_k(const float* __restrict__ spm, const float* __restrict__ spx,
                         const float* __restrict__ wsp, float* __restrict__ sa)
{
    int tx = threadIdx.x & 15, ty = threadIdx.x >> 4;
    int j = blockIdx.x*16 + tx;
    int i = blockIdx.y*16 + ty;
    int b = blockIdx.z;
    const float* m = spm + (size_t)b*HW;
    const float* x = spx + (size_t)b*HW;
    float s = 0.f;
    for(int kh=0;kh<7;kh++){
        int ii = i + kh - 3; if (ii<0||ii>=Hd) continue;
        for(int kw=0;kw<7;kw++){
            int jj = j + kw - 3; if (jj<0||jj>=Wd) continue;
            s += wsp[kh*7+kw]*m[ii*Wd+jj] + wsp[49+kh*7+kw]*x[ii*Wd+jj];
        }
    }
    sa[(size_t)b*HW + i*Wd + j] = 1.f / (1.f + expf(-s));
}

// ================= orchestration =================
extern "C" void kernel_launch(void* const* d_in, const int* in_sizes, int n_in,
                              void* d_out, int out_size, void* d_ws, size_t ws_size,
                              hipStream_t stream)
{
    const float* lf        = (const float*)d_in[0];
    const float* hf        = (const float*)d_in[1];
    const float* w_conv1_1 = (const float*)d_in[2];
    const float* b_conv1_1 = (const float*)d_in[3];
    const float* w_conv    = (const float*)d_in[4];
    const float* w_offset  = (const float*)d_in[5];
    const float* b_offset  = (const float*)d_in[6];
    const float* w_deform  = (const float*)d_in[7];
    const float* w_dil[4]  = {(const float*)d_in[8],(const float*)d_in[9],
                              (const float*)d_in[10],(const float*)d_in[11]};
    const float* w_conv1   = (const float*)d_in[12];
    const float* w_conv2   = (const float*)d_in[13];
    const float* w_fc1     = (const float*)d_in[14];
    const float* w_fc2     = (const float*)d_in[15];
    const float* w_sp      = (const float*)d_in[16];
    const float* w_conv1_2 = (const float*)d_in[17];
    const float* b_conv1_2 = (const float*)d_in[18];
    const float* w_conv3_3 = (const float*)d_in[19];
    float* out = (float*)d_out;

    float* ws = (float*)d_ws;
    size_t off_f = 0;
    auto alloc = [&](size_t n){ float* p = ws + off_f; off_f += n; return p; };
    const size_t S16 = (size_t)Bn*16*HW;

    float* hf_p  = alloc(S16);
    float* B16_0 = alloc(S16);              // t
    float* B16_1 = alloc(S16);              // deform out / conv2 pre-bn
    float* B16_2 = alloc(S16);              // dil conv out
    float* B64F  = ws;                      // final 64ch buffer aliases first 4 S16 bufs
    float* Boff  = alloc((size_t)Bn*18*HW);
    float* B64_0 = alloc((size_t)Bn*64*HW); // d2 / xx
    float* xk[4] = {alloc(S16),alloc(S16),alloc(S16),alloc(S16)};
    float* spm   = alloc((size_t)Bn*HW);
    float* spx   = alloc((size_t)Bn*HW);
    float* sa    = alloc((size_t)Bn*HW);
    float* pavg  = alloc(256);
    float* pmax  = alloc(256);
    float* ca    = alloc(256);
    float* stats = alloc(8192);             // fused-BN stat slots (per instance)
    (void)ws_size; (void)in_sizes; (void)n_in; (void)out_size;

    // stat-instance sub-allocation: C channels * 8 floats each
    int soff = 0;
    auto salloc = [&](int C){ float* p = stats + soff; soff += C*8; return p; };
    float* stA = salloc(16);
    float *stT[4], *stD[4], *stC1[4], *stC2[4];
    for(int k=0;k<4;k++){ stT[k]=salloc(16); stD[k]=salloc(16); stC1[k]=salloc(64); stC2[k]=salloc(16); }
    float* stXX  = salloc(64);
    float* stOut = salloc(64);

    dim3 blk(256);
    dim3 gtile(16,16,Bn);
    dim3 gapply16(HW/1024,16,Bn), gapply64(HW/1024,64,Bn);
    // PX=8 tile = 64x32 -> 8 row-blocks. gridy = 8 * (COUT/COB)
    dim3 g16_8(4,16,Bn);    // COUT=16 COB=8 (or 18/9): 2 chunks -> 256 blocks
    dim3 g64_8(4,32,Bn);    // COUT=64 COB=16: 4 chunks          -> 512 blocks
    dim3 g1x1_16(HW/1024, 2, Bn);   // conv1x1 COUT=16 COB=8
    dim3 g1x1_64(HW/1024, 4, Bn);   // conv1x1 COUT=64 COB=16
    const long long bs16 = 16LL*HW, bs64 = 64LL*HW;

    // zero all stat slots once, up front
    zero_k<<<dim3(8),blk,0,stream>>>(stats, soff);

    // Stage A: hf_p = relu(bn(conv1x1(hf)))
    conv1x1_k<64,16,8,0><<<g1x1_16,blk,0,stream>>>(
        hf, nullptr, nullptr, nullptr, w_conv1_1, b_conv1_1, hf_p, stA);
    bn_apply_k<<<gapply16,blk,0,stream>>>(hf_p, stA, 16, nullptr,0, nullptr,0, hf_p, 1);

    for(int k=0;k<4;k++){
        const float* prev; long long prev_bs;
        if (k==0){ prev = lf;      prev_bs = bs64; }
        else     { prev = xk[k-1]; prev_bs = bs16; }
        // xb = conv3x3(cat(prev, hf_p))  [cat fused via dual-input conv]
        conv3_k<16,16,16,8,1,8><<<g16_8,blk,0,stream>>>(
            prev, prev_bs, hf_p, nullptr, w_conv, nullptr, nullptr, nullptr, B16_0, stT[k]);
        const float* e1; long long e1bs; const float* e2 = nullptr; long long e2bs = 0;
        if (k==0){ e1 = lf + 16*HW; e1bs = bs64; }
        else if (k==3){ e1 = xk[2]; e1bs = bs16; }
        else { e1 = xk[k-1]; e1bs = bs16; e2 = lf + (size_t)(k+1)*16*HW; e2bs = bs64; }
        bn_apply_k<<<gapply16,blk,0,stream>>>(B16_0, stT[k], 16, e1,e1bs, e2,e2bs, B16_0, 0); // t
        // offset conv (has bias, no bn)
        conv3_k<16,0,18,9,1,8><<<g16_8,blk,0,stream>>>(
            B16_0, bs16, nullptr, nullptr, w_offset, b_offset, nullptr, nullptr, Boff, nullptr);
        deform_k<<<gtile,blk,0,stream>>>(B16_0, Boff, w_deform, B16_1);
        // dilated conv
        switch(k){
        case 0: conv3_k<16,0,16,8,1,8><<<g16_8,blk,0,stream>>>(B16_1, bs16, nullptr, nullptr, w_dil[0], nullptr, nullptr, nullptr, B16_2, stD[k]); break;
        case 1: conv3_k<16,0,16,8,2,8><<<g16_8,blk,0,stream>>>(B16_1, bs16, nullptr, nullptr, w_dil[1], nullptr, nullptr, nullptr, B16_2, stD[k]); break;
        case 2: conv3_k<16,0,16,8,3,8><<<g16_8,blk,0,stream>>>(B16_1, bs16, nullptr, nullptr, w_dil[2], nullptr, nullptr, nullptr, B16_2, stD[k]); break;
        case 3: conv3_k<16,0,16,8,4,8><<<g16_8,blk,0,stream>>>(B16_1, bs16, nullptr, nullptr, w_dil[3], nullptr, nullptr, nullptr, B16_2, stD[k]); break;
        }
        bn_apply_k<<<gapply16,blk,0,stream>>>(B16_2, stD[k], 16, nullptr,0, nullptr,0, B16_2, 0);
        // conv1: 16 -> 64 (4 out-chunks, PX8)
        conv3_k<16,0,64,16,1,8><<<g64_8,blk,0,stream>>>(
            B16_2, bs16, nullptr, nullptr, w_conv1, nullptr, nullptr, nullptr, B64_0, stC1[k]);
        bn_apply_k<<<gapply64,blk,0,stream>>>(B64_0, stC1[k], 64, nullptr,0, nullptr,0, B64_0, 0);
        // CBAM
        pool_k<<<Bn*64,blk,0,stream>>>(B64_0, pavg, pmax);
        ca_k<<<Bn,dim3(64),0,stream>>>(pavg, pmax, w_fc1, w_fc2, ca);
        spstats_k<<<dim3(256,Bn),blk,0,stream>>>(B64_0, ca, spm, spx);
        spconv_k<<<gtile,blk,0,stream>>>(spm, spx, w_sp, sa);
        // conv2 with fused ca (per-channel) and sa (per-pixel) input scaling
        conv3_k<64,0,16,8,1,8><<<g16_8,blk,0,stream>>>(
            B64_0, bs64, nullptr, nullptr, w_conv2, nullptr, ca, sa, B16_1, stC2[k]);
        bn_apply_k<<<gapply16,blk,0,stream>>>(B16_1, stC2[k], 16, nullptr,0, nullptr,0, xk[k], 0);
    }

    // Final: xx = relu(bn(conv1x1(cat4))), out = bn(conv3x3(lf + xx))
    // cat4 fused into conv1x1 (SPLIT=1 reads xk[0..3] directly)
    conv1x1_k<64,64,16,1><<<g1x1_64,blk,0,stream>>>(
        xk[0], xk[1], xk[2], xk[3], w_conv1_2, b_conv1_2, B64_0, stXX);
    bn_apply_k<<<gapply64,blk,0,stream>>>(B64_0, stXX, 64, nullptr,0, nullptr,0, B64_0, 1); // xx
    conv3_k<64,0,64,16,1,8><<<g64_8,blk,0,stream>>>(
        lf, bs64, nullptr, B64_0, w_conv3_3, nullptr, nullptr, nullptr, B64F, stOut);
    bn_apply_k<<<gapply64,blk,0,stream>>>(B64F, stOut, 64, nullptr,0, nullptr,0, out, 0);
}

// Round 5
// 4380.729 us; speedup vs baseline: 1.3403x; 1.3403x over previous
//
#include <hip/hip_runtime.h>
#include <math.h>

#define HW 65536
#define Wd 256
#define Hd 256
#define Bn 4

// stats layout per channel: [4 slots of sum][4 slots of sum2]  (float)
__device__ __forceinline__ void atomAddF(float* p, float v){
    __hip_atomic_fetch_add(p, v, __ATOMIC_RELAXED, __HIP_MEMORY_SCOPE_AGENT);
}

__global__ void zero_k(float* __restrict__ p, int n){
    for(int i = blockIdx.x*256 + threadIdx.x; i < n; i += gridDim.x*256) p[i] = 0.f;
}

// ================= vectorized direct 3x3 conv =================
// R2-proven structure: simple per-channel loop, PX px/thread, COB out-chans.
// ONE change vs R2: weights staged once in LDS (uniform ds_read broadcast
// instead of per-iteration s_load groups waiting inside the FMA block).
template<int CIN1,int CIN2,int COUT,int COB,int DIL,int PX>
__global__ __launch_bounds__(256) void conv3_k(
    const float* __restrict__ inA, long long a_bs,
    const float* __restrict__ inB,
    const float* __restrict__ add_in,
    const float* __restrict__ w, const float* __restrict__ bias,
    const float* __restrict__ scale_c, const float* __restrict__ scale_p,
    float* __restrict__ out, float* __restrict__ stats)
{
    constexpr int CIN = CIN1 + CIN2;
    constexpr int SP = 2*DIL + PX;
    constexpr int TPR = 64/PX;        // threads per 64-wide row
    constexpr int ROWS = 256/TPR;     // rows per block
    constexpr int IYB = Hd/ROWS;      // row-blocks
    int tx = threadIdx.x % TPR, ty = threadIdx.x / TPR;
    int j0 = blockIdx.x*64 + tx*PX;
    int iy = blockIdx.y % IYB;
    int chunk = blockIdx.y / IYB;
    int i = iy*ROWS + ty;
    int b = blockIdx.z;
    int o0 = chunk*COB;

    // stage this chunk's weights into LDS once (contiguous COB*CIN*9 block)
    __shared__ float wl[COB*CIN*9];
    for(int t=threadIdx.x; t<COB*CIN*9; t+=256)
        wl[t] = w[(size_t)o0*CIN*9 + t];
    __syncthreads();

    float acc[COB][PX];
#pragma unroll
    for(int o=0;o<COB;o++){
        float bv = bias ? bias[o0+o] : 0.f;
#pragma unroll
        for(int q=0;q<PX;q++) acc[o][q] = bv;
    }

    const float* spb = scale_p ? scale_p + (size_t)b*HW : nullptr;

    for(int c=0;c<CIN;c++){
        const float* cb;
        if (CIN2 == 0 || c < CIN1) cb = inA + (size_t)b*a_bs + (size_t)c*HW;
        else                       cb = inB + ((size_t)b*CIN2 + (c-CIN1))*HW;
        const float* ab = add_in ? add_in + (size_t)b*a_bs + (size_t)c*HW : nullptr;
        float sc = scale_c ? scale_c[b*CIN + c] : 1.f;

        float r[3][SP];
#pragma unroll
        for(int kh=0;kh<3;kh++){
#pragma unroll
            for(int t=0;t<SP;t++) r[kh][t] = 0.f;
            int ii = i + (kh-1)*DIL;
            if (ii < 0 || ii >= Hd) continue;
            const float* row = cb + ii*Wd;
#pragma unroll
            for(int q4=0;q4<PX/4;q4++){
                float4 c4 = *(const float4*)(row + j0 + q4*4);
                r[kh][DIL+q4*4+0]=c4.x; r[kh][DIL+q4*4+1]=c4.y;
                r[kh][DIL+q4*4+2]=c4.z; r[kh][DIL+q4*4+3]=c4.w;
            }
#pragma unroll
            for(int t=0;t<DIL;t++){
                int jl = j0 - DIL + t;
                if (jl >= 0) r[kh][t] = row[jl];
                int jr = j0 + PX + t;
                if (jr < Wd) r[kh][DIL+PX+t] = row[jr];
            }
            if (ab){
                const float* arow = ab + ii*Wd;
#pragma unroll
                for(int q4=0;q4<PX/4;q4++){
                    float4 a4 = *(const float4*)(arow + j0 + q4*4);
                    r[kh][DIL+q4*4+0]+=a4.x; r[kh][DIL+q4*4+1]+=a4.y;
                    r[kh][DIL+q4*4+2]+=a4.z; r[kh][DIL+q4*4+3]+=a4.w;
                }
#pragma unroll
                for(int t=0;t<DIL;t++){
                    int jl = j0 - DIL + t;
                    if (jl >= 0) r[kh][t] += arow[jl];
                    int jr = j0 + PX + t;
                    if (jr < Wd) r[kh][DIL+PX+t] += arow[jr];
                }
            }
            if (spb){
                const float* srow = spb + ii*Wd;
#pragma unroll
                for(int q4=0;q4<PX/4;q4++){
                    float4 s4 = *(const float4*)(srow + j0 + q4*4);
                    r[kh][DIL+q4*4+0]*=s4.x; r[kh][DIL+q4*4+1]*=s4.y;
                    r[kh][DIL+q4*4+2]*=s4.z; r[kh][DIL+q4*4+3]*=s4.w;
                }
#pragma unroll
                for(int t=0;t<DIL;t++){
                    int jl = j0 - DIL + t;
                    if (jl >= 0) r[kh][t] *= srow[jl];
                    int jr = j0 + PX + t;
                    if (jr < Wd) r[kh][DIL+PX+t] *= srow[jr];
                }
            }
            if (scale_c){
#pragma unroll
                for(int t=0;t<SP;t++) r[kh][t] *= sc;
            }
        }

#pragma unroll
        for(int o=0;o<COB;o++){
#pragma unroll
            for(int kh=0;kh<3;kh++){
#pragma unroll
                for(int kw=0;kw<3;kw++){
                    float ww = wl[(o*CIN + c)*9 + kh*3 + kw];
#pragma unroll
                    for(int q=0;q<PX;q++)
                        acc[o][q] = fmaf(ww, r[kh][kw*DIL + q], acc[o][q]);
                }
            }
        }
    }

    float* ob = out + ((size_t)b*COUT + o0)*HW + i*Wd + j0;
#pragma unroll
    for(int o=0;o<COB;o++){
#pragma unroll
        for(int q4=0;q4<PX/4;q4++){
            float4 v; v.x=acc[o][q4*4+0]; v.y=acc[o][q4*4+1];
            v.z=acc[o][q4*4+2]; v.w=acc[o][q4*4+3];
            *(float4*)(ob + (size_t)o*HW + q4*4) = v;
        }
    }

    if (stats){
#pragma unroll
        for(int o=0;o<COB;o++){
            float s = 0.f, s2 = 0.f;
#pragma unroll
            for(int q=0;q<PX;q++){ s += acc[o][q]; s2 += acc[o][q]*acc[o][q]; }
#pragma unroll
            for(int d=32;d>0;d>>=1){
                s  += __shfl_down(s,  d, 64);
                s2 += __shfl_down(s2, d, 64);
            }
            if ((threadIdx.x & 63) == 0){
                float* pc = stats + (size_t)(o0+o)*8 + ((threadIdx.x>>6)&3);
                atomAddF(pc,   s);
                atomAddF(pc+4, s2);
            }
        }
    }
}

// ================= conv 1x1 : PX=4 pixels/thread, COB-chunked channels =========
// SPLIT=1: input is the channel-concat of 4 buffers of 16 channels each.
template<int CIN,int COUT,int COB,int SPLIT>
__global__ __launch_bounds__(256) void conv1x1_k(
    const float* __restrict__ in0, const float* __restrict__ in1,
    const float* __restrict__ in2, const float* __restrict__ in3,
    const float* __restrict__ w, const float* __restrict__ bias,
    float* __restrict__ out, float* __restrict__ stats)
{
    int p = (blockIdx.x*256 + threadIdx.x)*4;
    int chunk = blockIdx.y;
    int b = blockIdx.z;
    int o0 = chunk*COB;

    float acc[COB][4];
#pragma unroll
    for(int o=0;o<COB;o++){
        float bv = bias ? bias[o0+o] : 0.f;
#pragma unroll
        for(int q=0;q<4;q++) acc[o][q] = bv;
    }

#pragma unroll 8
    for(int c=0;c<CIN;c++){
        const float* cb;
        if (SPLIT){
            const float* s = (c<16)?in0:(c<32)?in1:(c<48)?in2:in3;
            cb = s + ((size_t)b*16 + (c&15))*HW;
        } else {
            cb = in0 + ((size_t)b*CIN + c)*HW;
        }
        float4 v = *(const float4*)(cb + p);
#pragma unroll
        for(int o=0;o<COB;o++){
            float ww = w[(size_t)(o0+o)*CIN + c];
            acc[o][0] = fmaf(ww, v.x, acc[o][0]);
            acc[o][1] = fmaf(ww, v.y, acc[o][1]);
            acc[o][2] = fmaf(ww, v.z, acc[o][2]);
            acc[o][3] = fmaf(ww, v.w, acc[o][3]);
        }
    }

    float* ob = out + ((size_t)b*COUT + o0)*HW + p;
#pragma unroll
    for(int o=0;o<COB;o++){
        float4 v; v.x=acc[o][0]; v.y=acc[o][1]; v.z=acc[o][2]; v.w=acc[o][3];
        *(float4*)(ob + (size_t)o*HW) = v;
    }

    if (stats){
#pragma unroll
        for(int o=0;o<COB;o++){
            float s = 0.f, s2 = 0.f;
#pragma unroll
            for(int q=0;q<4;q++){ s += acc[o][q]; s2 += acc[o][q]*acc[o][q]; }
#pragma unroll
            for(int d=32;d>0;d>>=1){
                s  += __shfl_down(s,  d, 64);
                s2 += __shfl_down(s2, d, 64);
            }
            if ((threadIdx.x & 63) == 0){
                float* pc = stats + (size_t)(o0+o)*8 + ((threadIdx.x>>6)&3);
                atomAddF(pc,   s);
                atomAddF(pc+4, s2);
            }
        }
    }
}

// ===== BN apply, float4 (+extras with batch stride, +relu); m/r from fused stats =====
__global__ void bn_apply_k(const float* __restrict__ x, const float* __restrict__ stats, int C,
                           const float* __restrict__ e1, long long e1_bs,
                           const float* __restrict__ e2, long long e2_bs,
                           float* __restrict__ out, int relu)
{
    int p = (blockIdx.x*256 + threadIdx.x)*4;
    int c = blockIdx.y, b = blockIdx.z;
    const float* pc = stats + (size_t)c*8;
    float s  = pc[0]+pc[1]+pc[2]+pc[3];
    float s2 = pc[4]+pc[5]+pc[6]+pc[7];
    const float inv_n = 1.f / (float)((long long)Bn*HW);
    float m = s*inv_n;
    float r = rsqrtf(fmaxf(s2*inv_n - m*m, 0.f) + 1e-5f);
    size_t idx = ((size_t)b*C + c)*HW + p;
    float4 v = *(const float4*)(x + idx);
    v.x = (v.x-m)*r; v.y = (v.y-m)*r; v.z = (v.z-m)*r; v.w = (v.w-m)*r;
    if (e1){
        float4 a = *(const float4*)(e1 + (size_t)b*e1_bs + (size_t)c*HW + p);
        v.x+=a.x; v.y+=a.y; v.z+=a.z; v.w+=a.w;
    }
    if (e2){
        float4 a = *(const float4*)(e2 + (size_t)b*e2_bs + (size_t)c*HW + p);
        v.x+=a.x; v.y+=a.y; v.z+=a.z; v.w+=a.w;
    }
    if (relu){
        v.x=fmaxf(v.x,0.f); v.y=fmaxf(v.y,0.f); v.z=fmaxf(v.z,0.f); v.w=fmaxf(v.w,0.f);
    }
    *(float4*)(out + idx) = v;
}

// ================= deformable conv (exact reference boundary semantics) ============
__global__ void deform_k(const float* __restrict__ t, const float* __restrict__ off,
                         const float* __restrict__ w, float* __restrict__ out)
{
    int tx = threadIdx.x & 15, ty = threadIdx.x >> 4;
    int j = blockIdx.x*16 + tx;
    int i = blockIdx.y*16 + ty;
    int b = blockIdx.z;
    const float* tb = t + (size_t)b*16*HW;
    const float* ob = off + (size_t)b*18*HW + i*Wd + j;
    float acc[16];
#pragma unroll
    for(int o=0;o<16;o++) acc[o] = 0.f;

    for(int n=0;n<9;n++){
        float offx = ob[(size_t)(2*n)*HW];
        float offy = ob[(size_t)(2*n+1)*HW];
        float px = (float)(i + n/3) + offx;
        float py = (float)(j + n%3) + offy;
        float flx = floorf(px), fly = floorf(py);
        float qltx = fminf(fmaxf(flx,       0.f), 257.f);
        float qlty = fminf(fmaxf(fly,       0.f), 257.f);
        float qrbx = fminf(fmaxf(flx + 1.f, 0.f), 257.f);
        float qrby = fminf(fmaxf(fly + 1.f, 0.f), 257.f);
        if (px < 1.f || px > 256.f) px = flx;
        if (py < 1.f || py > 256.f) py = fly;
        px = fminf(fmaxf(px, 0.f), 257.f);
        py = fminf(fmaxf(py, 0.f), 257.f);
        float wx_lt = 1.f + (qltx - px);
        float wx_rb = 1.f - (qrbx - px);
        float wy_lt = 1.f + (qlty - py);
        float wy_rb = 1.f - (qrby - py);
        float glt = wx_lt*wy_lt, grb = wx_rb*wy_rb, glb = wx_lt*wy_rb, grt = wx_rb*wy_lt;
        int ix0 = (int)qltx - 1, iy0 = (int)qlty - 1;
        int ix1 = (int)qrbx - 1, iy1 = (int)qrby - 1;
        bool vx0 = (ix0>=0 && ix0<Hd), vx1 = (ix1>=0 && ix1<Hd);
        bool vy0 = (iy0>=0 && iy0<Wd), vy1 = (iy1>=0 && iy1<Wd);
        int i00 = ix0*Wd+iy0, i01 = ix0*Wd+iy1, i10 = ix1*Wd+iy0, i11 = ix1*Wd+iy1;
        float vals[16];
#pragma unroll
        for(int c=0;c<16;c++){
            const float* tc = tb + (size_t)c*HW;
            float v00 = (vx0&&vy0) ? tc[i00] : 0.f;
            float v11 = (vx1&&vy1) ? tc[i11] : 0.f;
            float v01 = (vx0&&vy1) ? tc[i01] : 0.f;
            float v10 = (vx1&&vy0) ? tc[i10] : 0.f;
            vals[c] = glt*v00 + grb*v11 + glb*v01 + grt*v10;
        }
#pragma unroll
        for(int o=0;o<16;o++){
            float a = acc[o];
#pragma unroll
            for(int c=0;c<16;c++) a += w[(o*16+c)*9 + n] * vals[c];
            acc[o] = a;
        }
    }
    float* outb = out + (size_t)b*16*HW + i*Wd + j;
#pragma unroll
    for(int o=0;o<16;o++) outb[(size_t)o*HW] = acc[o];
}

// ================= CBAM pieces =================
__global__ void pool_k(const float* __restrict__ x, float* __restrict__ pavg, float* __restrict__ pmax)
{
    int bc = blockIdx.x;
    int tid = threadIdx.x;
    const float* p = x + (size_t)bc*HW;
    float s = 0.f, mx = -1e30f;
    for(int i=tid;i<HW;i+=256){ float v = p[i]; s += v; mx = fmaxf(mx, v); }
    __shared__ float sh[512];
    sh[tid] = s; sh[256+tid] = mx;
    __syncthreads();
    for(int o=128;o>0;o>>=1){
        if (tid < o){ sh[tid] += sh[tid+o]; sh[256+tid] = fmaxf(sh[256+tid], sh[256+tid+o]); }
        __syncthreads();
    }
    if (tid==0){ pavg[bc] = sh[0] / (float)HW; pmax[bc] = sh[256]; }
}

__global__ void ca_k(const float* __restrict__ pavg, const float* __restrict__ pmax,
                     const float* __restrict__ w1, const float* __restrict__ w2,
                     float* __restrict__ ca)
{
    int b = blockIdx.x;
    int tid = threadIdx.x;   // 64 threads
    __shared__ float ha[4], hm[4];
    if (tid < 4){
        float sa = 0.f, sm = 0.f;
        for(int c=0;c<64;c++){
            sa += w1[tid*64+c] * pavg[b*64+c];
            sm += w1[tid*64+c] * pmax[b*64+c];
        }
        ha[tid] = fmaxf(sa, 0.f);
        hm[tid] = fmaxf(sm, 0.f);
    }
    __syncthreads();
    float s = 0.f;
    for(int h=0;h<4;h++) s += w2[tid*4+h] * (ha[h] + hm[h]);
    ca[b*64+tid] = 1.f / (1.f + expf(-s));
}

__global__ void spstats_k(const float* __restrict__ x, const float* __restrict__ ca,
                          float* __restrict__ spm, float* __restrict__ spx)
{
    int p = blockIdx.x*256 + threadIdx.x;
    int b = blockIdx.y;
    const float* xb = x + (size_t)b*64*HW + p;
    const float* cb = ca + b*64;
    float s = 0.f, mx = -1e30f;
    for(int c=0;c<64;c++){
        float v = xb[(size_t)c*HW] * cb[c];
        s += v; mx = fmaxf(mx, v);
    }
    spm[(size_t)b*HW+p] = s * (1.f/64.f);
    spx[(size_t)b*HW+p] = mx;
}

__global__ void spconv_k(const float* __restrict__ spm, const float* __restrict__ spx,
                         const float* __restrict__ wsp, float* __restrict__ sa)
{
    int tx = threadIdx.x & 15, ty = threadIdx.x >> 4;
    int j = blockIdx.x*16 + tx;
    int i = blockIdx.y*16 + ty;
    int b = blockIdx.z;
    const float* m = spm + (size_t)b*HW;
    const float* x = spx + (size_t)b*HW;
    float s = 0.f;
    for(int kh=0;kh<7;kh++){
        int ii = i + kh - 3; if (ii<0||ii>=Hd) continue;
        for(int kw=0;kw<7;kw++){
            int jj = j + kw - 3; if (jj<0||jj>=Wd) continue;
            s += wsp[kh*7+kw]*m[ii*Wd+jj] + wsp[49+kh*7+kw]*x[ii*Wd+jj];
        }
    }
    sa[(size_t)b*HW + i*Wd + j] = 1.f / (1.f + expf(-s));
}

// ================= orchestration =================
extern "C" void kernel_launch(void* const* d_in, const int* in_sizes, int n_in,
                              void* d_out, int out_size, void* d_ws, size_t ws_size,
                              hipStream_t stream)
{
    const float* lf        = (const float*)d_in[0];
    const float* hf        = (const float*)d_in[1];
    const float* w_conv1_1 = (const float*)d_in[2];
    const float* b_conv1_1 = (const float*)d_in[3];
    const float* w_conv    = (const float*)d_in[4];
    const float* w_offset  = (const float*)d_in[5];
    const float* b_offset  = (const float*)d_in[6];
    const float* w_deform  = (const float*)d_in[7];
    const float* w_dil[4]  = {(const float*)d_in[8],(const float*)d_in[9],
                              (const float*)d_in[10],(const float*)d_in[11]};
    const float* w_conv1   = (const float*)d_in[12];
    const float* w_conv2   = (const float*)d_in[13];
    const float* w_fc1     = (const float*)d_in[14];
    const float* w_fc2     = (const float*)d_in[15];
    const float* w_sp      = (const float*)d_in[16];
    const float* w_conv1_2 = (const float*)d_in[17];
    const float* b_conv1_2 = (const float*)d_in[18];
    const float* w_conv3_3 = (const float*)d_in[19];
    float* out = (float*)d_out;

    float* ws = (float*)d_ws;
    size_t off_f = 0;
    auto alloc = [&](size_t n){ float* p = ws + off_f; off_f += n; return p; };
    const size_t S16 = (size_t)Bn*16*HW;

    float* hf_p  = alloc(S16);
    float* B16_0 = alloc(S16);              // t
    float* B16_1 = alloc(S16);              // deform out / conv2 pre-bn
    float* B16_2 = alloc(S16);              // dil conv out
    float* B64F  = ws;                      // final 64ch buffer aliases first 4 S16 bufs
    float* Boff  = alloc((size_t)Bn*18*HW);
    float* B64_0 = alloc((size_t)Bn*64*HW); // d2 / xx
    float* xk[4] = {alloc(S16),alloc(S16),alloc(S16),alloc(S16)};
    float* spm   = alloc((size_t)Bn*HW);
    float* spx   = alloc((size_t)Bn*HW);
    float* sa    = alloc((size_t)Bn*HW);
    float* pavg  = alloc(256);
    float* pmax  = alloc(256);
    float* ca    = alloc(256);
    float* stats = alloc(8192);             // fused-BN stat slots (per instance)
    (void)ws_size; (void)in_sizes; (void)n_in; (void)out_size;

    // stat-instance sub-allocation: C channels * 8 floats each
    int soff = 0;
    auto salloc = [&](int C){ float* p = stats + soff; soff += C*8; return p; };
    float* stA = salloc(16);
    float *stT[4], *stD[4], *stC1[4], *stC2[4];
    for(int k=0;k<4;k++){ stT[k]=salloc(16); stD[k]=salloc(16); stC1[k]=salloc(64); stC2[k]=salloc(16); }
    float* stXX  = salloc(64);
    float* stOut = salloc(64);

    dim3 blk(256);
    dim3 gtile(16,16,Bn);
    dim3 gapply16(HW/1024,16,Bn), gapply64(HW/1024,64,Bn);
    // PX=8 tile = 64x32 -> 8 row-blocks. gridy = 8 * (COUT/COB)
    dim3 g16_8(4,16,Bn);    // COUT=16 COB=8 (or 18/9): 2 chunks -> 256 blocks
    dim3 g64_8(4,32,Bn);    // COUT=64 COB=16: 4 chunks          -> 512 blocks
    dim3 g1x1_16(HW/1024, 2, Bn);   // conv1x1 COUT=16 COB=8
    dim3 g1x1_64(HW/1024, 4, Bn);   // conv1x1 COUT=64 COB=16
    const long long bs16 = 16LL*HW, bs64 = 64LL*HW;

    // zero all stat slots once, up front
    zero_k<<<dim3(8),blk,0,stream>>>(stats, soff);

    // Stage A: hf_p = relu(bn(conv1x1(hf)))
    conv1x1_k<64,16,8,0><<<g1x1_16,blk,0,stream>>>(
        hf, nullptr, nullptr, nullptr, w_conv1_1, b_conv1_1, hf_p, stA);
    bn_apply_k<<<gapply16,blk,0,stream>>>(hf_p, stA, 16, nullptr,0, nullptr,0, hf_p, 1);

    for(int k=0;k<4;k++){
        const float* prev; long long prev_bs;
        if (k==0){ prev = lf;      prev_bs = bs64; }
        else     { prev = xk[k-1]; prev_bs = bs16; }
        // xb = conv3x3(cat(prev, hf_p))  [cat fused via dual-input conv]
        conv3_k<16,16,16,8,1,8><<<g16_8,blk,0,stream>>>(
            prev, prev_bs, hf_p, nullptr, w_conv, nullptr, nullptr, nullptr, B16_0, stT[k]);
        const float* e1; long long e1bs; const float* e2 = nullptr; long long e2bs = 0;
        if (k==0){ e1 = lf + 16*HW; e1bs = bs64; }
        else if (k==3){ e1 = xk[2]; e1bs = bs16; }
        else { e1 = xk[k-1]; e1bs = bs16; e2 = lf + (size_t)(k+1)*16*HW; e2bs = bs64; }
        bn_apply_k<<<gapply16,blk,0,stream>>>(B16_0, stT[k], 16, e1,e1bs, e2,e2bs, B16_0, 0); // t
        // offset conv (has bias, no bn)
        conv3_k<16,0,18,9,1,8><<<g16_8,blk,0,stream>>>(
            B16_0, bs16, nullptr, nullptr, w_offset, b_offset, nullptr, nullptr, Boff, nullptr);
        deform_k<<<gtile,blk,0,stream>>>(B16_0, Boff, w_deform, B16_1);
        // dilated conv
        switch(k){
        case 0: conv3_k<16,0,16,8,1,8><<<g16_8,blk,0,stream>>>(B16_1, bs16, nullptr, nullptr, w_dil[0], nullptr, nullptr, nullptr, B16_2, stD[k]); break;
        case 1: conv3_k<16,0,16,8,2,8><<<g16_8,blk,0,stream>>>(B16_1, bs16, nullptr, nullptr, w_dil[1], nullptr, nullptr, nullptr, B16_2, stD[k]); break;
        case 2: conv3_k<16,0,16,8,3,8><<<g16_8,blk,0,stream>>>(B16_1, bs16, nullptr, nullptr, w_dil[2], nullptr, nullptr, nullptr, B16_2, stD[k]); break;
        case 3: conv3_k<16,0,16,8,4,8><<<g16_8,blk,0,stream>>>(B16_1, bs16, nullptr, nullptr, w_dil[3], nullptr, nullptr, nullptr, B16_2, stD[k]); break;
        }
        bn_apply_k<<<gapply16,blk,0,stream>>>(B16_2, stD[k], 16, nullptr,0, nullptr,0, B16_2, 0);
        // conv1: 16 -> 64 (4 out-chunks, PX8)
        conv3_k<16,0,64,16,1,8><<<g64_8,blk,0,stream>>>(
            B16_2, bs16, nullptr, nullptr, w_conv1, nullptr, nullptr, nullptr, B64_0, stC1[k]);
        bn_apply_k<<<gapply64,blk,0,stream>>>(B64_0, stC1[k], 64, nullptr,0, nullptr,0, B64_0, 0);
        // CBAM
        pool_k<<<Bn*64,blk,0,stream>>>(B64_0, pavg, pmax);
        ca_k<<<Bn,dim3(64),0,stream>>>(pavg, pmax, w_fc1, w_fc2, ca);
        spstats_k<<<dim3(256,Bn),blk,0,stream>>>(B64_0, ca, spm, spx);
        spconv_k<<<gtile,blk,0,stream>>>(spm, spx, w_sp, sa);
        // conv2 with fused ca (per-channel) and sa (per-pixel) input scaling
        conv3_k<64,0,16,8,1,8><<<g16_8,blk,0,stream>>>(
            B64_0, bs64, nullptr, nullptr, w_conv2, nullptr, ca, sa, B16_1, stC2[k]);
        bn_apply_k<<<gapply16,blk,0,stream>>>(B16_1, stC2[k], 16, nullptr,0, nullptr,0, xk[k], 0);
    }

    // Final: xx = relu(bn(conv1x1(cat4))), out = bn(conv3x3(lf + xx))
    // cat4 fused into conv1x1 (SPLIT=1 reads xk[0..3] directly)
    conv1x1_k<64,64,16,1><<<g1x1_64,blk,0,stream>>>(
        xk[0], xk[1], xk[2], xk[3], w_conv1_2, b_conv1_2, B64_0, stXX);
    bn_apply_k<<<gapply64,blk,0,stream>>>(B64_0, stXX, 64, nullptr,0, nullptr,0, B64_0, 1); // xx
    conv3_k<64,0,64,16,1,8><<<g64_8,blk,0,stream>>>(
        lf, bs64, nullptr, B64_0, w_conv3_3, nullptr, nullptr, nullptr, B64F, stOut);
    bn_apply_k<<<gapply64,blk,0,stream>>>(B64F, stOut, 64, nullptr,0, nullptr,0, out, 0);
}